// Round 1
// baseline (1195.010 us; speedup 1.0000x reference)
//
#include <hip/hip_runtime.h>
#include <hip/hip_bf16.h>

// HGNN: out = BN(ReLU( segmax( BN(ReLU(concat(lf[li], dcoor) @ W1 + b1)) ) @ W2 + b2))
// Decomposition:
//   G[n,f]  = (last_features @ W1[:300] + b1)  as bf16   (dense GEMM, no gather)
//   y[e,f]  = ReLU(G[li[e],f] + delta[e] . Wc[:,f])       (edge pass, 3 FMA/elem)
//   BN1 is per-feature affine a*y+c, sign(a)=sign(g1) known upfront -> aggregate
//   z = sign(g1)*y with atomicMax on order-preserving uint encoding; fixup pass
//   applies agg = |a1|*dec(maxz) + c1, encoded-0 => empty segment => 0.
//   out_pre = ReLU(agg @ W2 + b2) -> d_out, stats -> affine in place.

#define NPART 256

__device__ __forceinline__ unsigned enc_f32(float x) {
    unsigned u = __float_as_uint(x);
    return (u & 0x80000000u) ? ~u : (u | 0x80000000u);
}
__device__ __forceinline__ float dec_f32(unsigned e) {
    unsigned u = (e & 0x80000000u) ? (e & 0x7fffffffu) : ~e;
    return __uint_as_float(u);
}

// ---------- tiled fp32 GEMM: C[M,N] = A[M,K] @ B[K,N] + bias ----------
// MODE 0: store bf16 (G path, no ReLU)
// MODE 1: ReLU, store fp32 to outF, accumulate per-feature sum/sumsq partials
template<int MODE>
__launch_bounds__(256)
__global__ void gemm_kernel(const float* __restrict__ A, int lda, int M,
                            const float* __restrict__ B, int ldb,
                            const float* __restrict__ bias,
                            int N, int K,
                            __hip_bfloat16* __restrict__ outBF,
                            float* __restrict__ outF,
                            float* __restrict__ part)
{
    __shared__ float As[16][68];   // A^T tile: [k][m], padded for b128 alignment
    __shared__ float Bs[16][68];   // B tile:   [k][n]
    __shared__ float sSum[64], sSq[64];

    const int tid = threadIdx.x;
    const int tx = tid & 15, ty = tid >> 4;
    const int m0 = blockIdx.x * 64, n0 = blockIdx.y * 64;

    const int am = tid >> 2;            // 0..63  (A row within tile)
    const int ak = (tid & 3) * 4;       // 0,4,8,12
    const int bk = tid >> 4;            // 0..15
    const int bn = (tid & 15) * 4;      // 0..60

    float acc[4][4] = {};

    for (int k0 = 0; k0 < K; k0 += 16) {
        float4 a4 = {0.f, 0.f, 0.f, 0.f};
        const int row = m0 + am;
        if (row < M && (k0 + ak) < K)   // K%4==0: chunk fully in or out
            a4 = *reinterpret_cast<const float4*>(&A[(long)row * lda + k0 + ak]);
        As[ak + 0][am] = a4.x; As[ak + 1][am] = a4.y;
        As[ak + 2][am] = a4.z; As[ak + 3][am] = a4.w;

        float4 b4 = {0.f, 0.f, 0.f, 0.f};
        if ((k0 + bk) < K && (n0 + bn) < N)  // N%4==0
            b4 = *reinterpret_cast<const float4*>(&B[(long)(k0 + bk) * ldb + n0 + bn]);
        *reinterpret_cast<float4*>(&Bs[bk][bn]) = b4;
        __syncthreads();

        #pragma unroll
        for (int k = 0; k < 16; ++k) {
            float4 av = *reinterpret_cast<const float4*>(&As[k][ty * 4]);
            float4 bv = *reinterpret_cast<const float4*>(&Bs[k][tx * 4]);
            float aa[4] = {av.x, av.y, av.z, av.w};
            float bb[4] = {bv.x, bv.y, bv.z, bv.w};
            #pragma unroll
            for (int i = 0; i < 4; ++i)
                #pragma unroll
                for (int j = 0; j < 4; ++j)
                    acc[i][j] = fmaf(aa[i], bb[j], acc[i][j]);
        }
        __syncthreads();
    }

    float colsum[4] = {}, colsq[4] = {};
    #pragma unroll
    for (int i = 0; i < 4; ++i) {
        const int r = m0 + ty * 4 + i;
        #pragma unroll
        for (int j = 0; j < 4; ++j) {
            const int c = n0 + tx * 4 + j;
            if (r < M && c < N) {
                float v = acc[i][j] + bias[c];
                if (MODE == 0) {
                    outBF[(long)r * N + c] = __float2bfloat16(v);
                } else {
                    v = fmaxf(v, 0.f);
                    outF[(long)r * N + c] = v;
                    colsum[j] += v; colsq[j] += v * v;
                }
            }
        }
    }

    if (MODE == 1) {
        if (tid < 64) { sSum[tid] = 0.f; sSq[tid] = 0.f; }
        __syncthreads();
        #pragma unroll
        for (int j = 0; j < 4; ++j) {
            atomicAdd(&sSum[tx * 4 + j], colsum[j]);
            atomicAdd(&sSq[tx * 4 + j], colsq[j]);
        }
        __syncthreads();
        const int slot = (blockIdx.x + blockIdx.y * gridDim.x) & (NPART - 1);
        if (tid < 64 && (n0 + tid) < N) {
            atomicAdd(&part[slot * 600 + n0 + tid], sSum[tid]);
            atomicAdd(&part[slot * 600 + 300 + n0 + tid], sSq[tid]);
        }
    }
}

// ---------- edge pass: y = ReLU(G[li] + delta.Wc); stats + encoded atomicMax ----------
__launch_bounds__(256)
__global__ void edge_pass(const __hip_bfloat16* __restrict__ Gb,
                          const float* __restrict__ last_coors,
                          const float* __restrict__ cur_coors,
                          const int* __restrict__ last_idx,
                          const int* __restrict__ cur_idx,
                          const float* __restrict__ Wc,   // rows 300..302 of W1, 3x300
                          const float* __restrict__ g1,
                          unsigned* __restrict__ zbuf,    // N_cur x 300, encoded, init 0
                          float* __restrict__ part1,
                          int E)
{
    __shared__ float sWc0[300], sWc1[300], sWc2[300];
    __shared__ int sRow[64], sCi[64];
    __shared__ float sD0[64], sD1[64], sD2[64];

    const int tid = threadIdx.x;
    for (int i = tid; i < 300; i += 256) {
        sWc0[i] = Wc[i]; sWc1[i] = Wc[300 + i]; sWc2[i] = Wc[600 + i];
    }

    const int f0 = tid;
    const int f1 = 256 + tid;
    const bool has1 = (f1 < 300);
    const float sgn0 = (g1[f0] < 0.f) ? -1.f : 1.f;
    const float sgn1 = has1 ? ((g1[f1] < 0.f) ? -1.f : 1.f) : 1.f;

    const int e0 = blockIdx.x * 64;
    const int ecnt = min(64, E - e0);

    if (tid < 64 && tid < ecnt) {
        const int e = e0 + tid;
        const int li = last_idx[e], ci = cur_idx[e];
        sRow[tid] = li * 300;
        sCi[tid]  = ci * 300;
        sD0[tid] = last_coors[li * 3 + 0] - cur_coors[ci * 3 + 0];
        sD1[tid] = last_coors[li * 3 + 1] - cur_coors[ci * 3 + 1];
        sD2[tid] = last_coors[li * 3 + 2] - cur_coors[ci * 3 + 2];
    }
    __syncthreads();

    float sum0 = 0.f, sq0 = 0.f, sum1 = 0.f, sq1 = 0.f;
    for (int i = 0; i < ecnt; ++i) {
        const int row = sRow[i], cz = sCi[i];
        const float d0 = sD0[i], d1 = sD1[i], d2 = sD2[i];
        {
            float y = __bfloat162float(Gb[row + f0])
                    + d0 * sWc0[f0] + d1 * sWc1[f0] + d2 * sWc2[f0];
            y = fmaxf(y, 0.f);
            sum0 += y; sq0 += y * y;
            const unsigned ev = enc_f32(sgn0 * y);
            unsigned* ap = &zbuf[cz + f0];
            if (ev > *ap) atomicMax(ap, ev);   // stale read only under-reads: safe
        }
        if (has1) {
            float y = __bfloat162float(Gb[row + f1])
                    + d0 * sWc0[f1] + d1 * sWc1[f1] + d2 * sWc2[f1];
            y = fmaxf(y, 0.f);
            sum1 += y; sq1 += y * y;
            const unsigned ev = enc_f32(sgn1 * y);
            unsigned* ap = &zbuf[cz + f1];
            if (ev > *ap) atomicMax(ap, ev);
        }
    }

    const int slot = blockIdx.x & (NPART - 1);
    atomicAdd(&part1[slot * 600 + f0], sum0);
    atomicAdd(&part1[slot * 600 + 300 + f0], sq0);
    if (has1) {
        atomicAdd(&part1[slot * 600 + f1], sum1);
        atomicAdd(&part1[slot * 600 + 300 + f1], sq1);
    }
}

// ---------- reduce partials -> per-feature affine (a, c) ----------
__global__ void stats_finalize(const float* __restrict__ part,
                               const float* __restrict__ g,
                               const float* __restrict__ be,
                               float invCnt, float* __restrict__ ac)
{
    const int t = threadIdx.x;
    if (t >= 300) return;
    float sum = 0.f, sq = 0.f;
    for (int p = 0; p < NPART; ++p) {
        sum += part[p * 600 + t];
        sq  += part[p * 600 + 300 + t];
    }
    const float mean = sum * invCnt;
    const float var = fmaxf(sq * invCnt - mean * mean, 0.f);
    const float inv = rsqrtf(var + 1e-5f);
    const float a = g[t] * inv;
    ac[t] = a;
    ac[300 + t] = be[t] - mean * a;
}

// ---------- decode zbuf -> agg (fp32, in place) ----------
__global__ void agg_finalize(unsigned* __restrict__ zbuf,
                             const float* __restrict__ ac1)
{
    const int t = threadIdx.x;
    if (t >= 300) return;
    const long i = (long)blockIdx.x * 300 + t;
    const unsigned u = zbuf[i];
    float v = 0.f;                      // encoded 0 == no edge wrote == empty segment
    if (u != 0u) v = fabsf(ac1[t]) * dec_f32(u) + ac1[300 + t];
    reinterpret_cast<float*>(zbuf)[i] = v;
}

// ---------- apply BN2 affine to d_out in place ----------
__global__ void finalize_out(float* __restrict__ out,
                             const float* __restrict__ ac2)
{
    const int t = threadIdx.x;
    if (t >= 300) return;
    const long i = (long)blockIdx.x * 300 + t;
    out[i] = ac2[t] * out[i] + ac2[300 + t];
}

extern "C" void kernel_launch(void* const* d_in, const int* in_sizes, int n_in,
                              void* d_out, int out_size, void* d_ws, size_t ws_size,
                              hipStream_t stream)
{
    const float* last_coors    = (const float*)d_in[0];
    const float* last_features = (const float*)d_in[1];
    const float* cur_coors     = (const float*)d_in[2];
    const int*   cur_idx       = (const int*)d_in[3];
    const int*   last_idx      = (const int*)d_in[4];
    const float* W1  = (const float*)d_in[5];
    const float* b1  = (const float*)d_in[6];
    const float* g1  = (const float*)d_in[7];
    const float* be1 = (const float*)d_in[8];
    const float* W2  = (const float*)d_in[9];
    const float* b2  = (const float*)d_in[10];
    const float* g2  = (const float*)d_in[11];
    const float* be2 = (const float*)d_in[12];
    float* out = (float*)d_out;

    const int N_last = in_sizes[0] / 3;
    const int N_cur  = in_sizes[2] / 3;
    const int E      = in_sizes[3];

    char* ws = (char*)d_ws;
    size_t off = 0;
    __hip_bfloat16* Gb = (__hip_bfloat16*)(ws + off);
    off += (size_t)N_last * 300 * 2;  off = (off + 255) & ~(size_t)255;
    unsigned* zbuf = (unsigned*)(ws + off);
    off += (size_t)N_cur * 300 * 4;   off = (off + 255) & ~(size_t)255;
    float* part1 = (float*)(ws + off); off += (size_t)NPART * 600 * 4;
    float* part2 = (float*)(ws + off); off += (size_t)NPART * 600 * 4;
    float* ac1   = (float*)(ws + off); off += 600 * 4;
    float* ac2   = (float*)(ws + off); off += 600 * 4;

    hipMemsetAsync(zbuf, 0, (size_t)N_cur * 300 * 4, stream);
    hipMemsetAsync(part1, 0, (size_t)NPART * 600 * 4, stream);
    hipMemsetAsync(part2, 0, (size_t)NPART * 600 * 4, stream);

    // G = last_features @ W1[:300] + b1  (bf16)
    dim3 gridG((N_last + 63) / 64, (300 + 63) / 64);
    gemm_kernel<0><<<gridG, 256, 0, stream>>>(last_features, 300, N_last,
                                              W1, 300, b1, 300, 300,
                                              Gb, nullptr, nullptr);

    // edge pass: stats1 partials + encoded segment max
    const int nEB = (E + 63) / 64;
    edge_pass<<<nEB, 256, 0, stream>>>(Gb, last_coors, cur_coors,
                                       last_idx, cur_idx,
                                       W1 + 300 * 300, g1, zbuf, part1, E);

    stats_finalize<<<1, 320, 0, stream>>>(part1, g1, be1, 1.0f / (float)E, ac1);
    agg_finalize<<<N_cur, 320, 0, stream>>>(zbuf, ac1);

    // out_pre = ReLU(agg @ W2 + b2), stats2 partials
    dim3 grid2((N_cur + 63) / 64, (300 + 63) / 64);
    gemm_kernel<1><<<grid2, 256, 0, stream>>>((const float*)zbuf, 300, N_cur,
                                              W2, 300, b2, 300, 300,
                                              nullptr, out, part2);

    stats_finalize<<<1, 320, 0, stream>>>(part2, g2, be2, 1.0f / (float)N_cur, ac2);
    finalize_out<<<N_cur, 320, 0, stream>>>(out, ac2);
}

// Round 2
// 972.559 us; speedup vs baseline: 1.2287x; 1.2287x over previous
//
#include <hip/hip_runtime.h>
#include <hip/hip_bf16.h>

// HGNN: out = BN(ReLU( segmax( BN(ReLU(concat(lf[li], dcoor) @ W1 + b1)) ) @ W2 + b2))
// Decomposition:
//   G[n,f]  = (last_features @ W1[:300] + b1)  as bf16   (MFMA GEMM, no gather)
//   y[e,f]  = ReLU(G[li[e],f] + delta[e] . Wc[:,f])      (edge pass, 3 FMA/elem)
//   BN1 is per-feature affine a*y+c, sign(a)=sign(g1) known upfront -> aggregate
//   z = sign(g1)*y with atomicMax on order-preserving uint encoding; fixup pass
//   applies agg = |a1|*dec(maxz) + c1, encoded-0 => empty segment => 0.
//   out_pre = ReLU(agg @ W2 + b2) -> d_out (MFMA GEMM, stats fused), affine in place.

#define NPART 64

typedef __bf16 bf16_t;
typedef __bf16 bf16x4 __attribute__((ext_vector_type(4)));
typedef __bf16 bf16x8 __attribute__((ext_vector_type(8)));
typedef float f32x4 __attribute__((ext_vector_type(4)));

__device__ __forceinline__ unsigned enc_f32(float x) {
    unsigned u = __float_as_uint(x);
    return (u & 0x80000000u) ? ~u : (u | 0x80000000u);
}
__device__ __forceinline__ float dec_f32(unsigned e) {
    unsigned u = (e & 0x80000000u) ? (e & 0x7fffffffu) : ~e;
    return __uint_as_float(u);
}

// ---------- pack W (fp32 [K=300][N=300] row-major) -> WT bf16 [384][320] = [n][k], zero-padded ----------
__global__ void pack_wt(const float* __restrict__ W, bf16_t* __restrict__ WT)
{
    const int idx = blockIdx.x * 256 + threadIdx.x;   // 384*320 = 122880
    if (idx >= 384 * 320) return;
    const int n = idx / 320, k = idx % 320;
    float v = (n < 300 && k < 300) ? W[k * 300 + n] : 0.f;
    WT[idx] = (bf16_t)v;
}

// ---------- MFMA bf16 GEMM: C[M,300] = A[M,300] @ W + bias ----------
// A fp32 row-major (lda), W pre-packed bf16 WT[384][320] = [n][k].
// MODE 0: store bf16 to outBF (G path, no ReLU)
// MODE 1: ReLU, store fp32 to outF, per-feature sum/sumsq partials to part
template<int MODE>
__launch_bounds__(256)
__global__ void gemm_mfma(const float* __restrict__ A, int lda, int M,
                          const bf16_t* __restrict__ WT,
                          const float* __restrict__ bias,
                          bf16_t* __restrict__ outBF,
                          float* __restrict__ outF,
                          float* __restrict__ part)
{
    __shared__ bf16_t As[128][72];   // [m][k], pad 64->72 (16B-aligned rows: 144 B)
    __shared__ bf16_t Bs[128][72];   // [n][k]
    __shared__ float sSum[128], sSq[128];

    const int tid  = threadIdx.x;
    const int lane = tid & 63, wv = tid >> 6;
    const int wm = wv & 1, wn = wv >> 1;         // wave -> 64x64 quadrant
    const int m0 = blockIdx.x * 128, n0 = blockIdx.y * 128;
    const int rl = lane & 15, quad = lane >> 4;

    if (MODE == 1 && tid < 128) { sSum[tid] = 0.f; sSq[tid] = 0.f; }

    f32x4 acc[4][4];
    #pragma unroll
    for (int i = 0; i < 4; ++i)
        #pragma unroll
        for (int j = 0; j < 4; ++j)
            acc[i][j] = (f32x4){0.f, 0.f, 0.f, 0.f};

    for (int k0 = 0; k0 < 320; k0 += 64) {
        // stage A tile (fp32 -> bf16): 128 rows x 64 k
        #pragma unroll
        for (int i = 0; i < 8; ++i) {
            const int id = i * 256 + tid;
            const int r = id >> 4, kc = (id & 15) * 4;
            const int gr = m0 + r, gk = k0 + kc;
            float4 a4 = {0.f, 0.f, 0.f, 0.f};
            if (gr < M && gk < 300)   // 300%4==0: float4 chunk fully valid or not
                a4 = *reinterpret_cast<const float4*>(&A[(long)gr * lda + gk]);
            bf16x4 b4 = {(bf16_t)a4.x, (bf16_t)a4.y, (bf16_t)a4.z, (bf16_t)a4.w};
            *reinterpret_cast<bf16x4*>(&As[r][kc]) = b4;
        }
        // stage B tile (pre-packed bf16, no masks: WT padded to 384x320)
        #pragma unroll
        for (int i = 0; i < 4; ++i) {
            const int id = i * 256 + tid;
            const int n = id >> 3, kc = (id & 7) * 8;
            bf16x8 w8 = *reinterpret_cast<const bf16x8*>(&WT[(long)(n0 + n) * 320 + k0 + kc]);
            *reinterpret_cast<bf16x8*>(&Bs[n][kc]) = w8;
        }
        __syncthreads();

        #pragma unroll
        for (int kk = 0; kk < 2; ++kk) {
            const int kb = kk * 32 + quad * 8;
            bf16x8 af[4], bfr[4];
            #pragma unroll
            for (int mi = 0; mi < 4; ++mi)
                af[mi] = *reinterpret_cast<const bf16x8*>(&As[wm * 64 + mi * 16 + rl][kb]);
            #pragma unroll
            for (int nj = 0; nj < 4; ++nj)
                bfr[nj] = *reinterpret_cast<const bf16x8*>(&Bs[wn * 64 + nj * 16 + rl][kb]);
            #pragma unroll
            for (int mi = 0; mi < 4; ++mi)
                #pragma unroll
                for (int nj = 0; nj < 4; ++nj)
                    acc[mi][nj] = __builtin_amdgcn_mfma_f32_16x16x32_bf16(
                        af[mi], bfr[nj], acc[mi][nj], 0, 0, 0);
        }
        __syncthreads();
    }

    // epilogue: C/D layout col = lane&15, row = quad*4 + reg  [m89-verified]
    if (MODE == 0) {
        #pragma unroll
        for (int mi = 0; mi < 4; ++mi)
            #pragma unroll
            for (int nj = 0; nj < 4; ++nj)
                #pragma unroll
                for (int reg = 0; reg < 4; ++reg) {
                    const int r = m0 + wm * 64 + mi * 16 + quad * 4 + reg;
                    const int c = n0 + wn * 64 + nj * 16 + rl;
                    if (r < M && c < 300)
                        outBF[(long)r * 300 + c] = (bf16_t)(acc[mi][nj][reg] + bias[c]);
                }
    } else {
        float csum[4] = {}, csq[4] = {};
        #pragma unroll
        for (int mi = 0; mi < 4; ++mi)
            #pragma unroll
            for (int nj = 0; nj < 4; ++nj)
                #pragma unroll
                for (int reg = 0; reg < 4; ++reg) {
                    const int r = m0 + wm * 64 + mi * 16 + quad * 4 + reg;
                    const int c = n0 + wn * 64 + nj * 16 + rl;
                    if (r < M && c < 300) {
                        float v = fmaxf(acc[mi][nj][reg] + bias[c], 0.f);
                        outF[(long)r * 300 + c] = v;
                        csum[nj] += v; csq[nj] += v * v;
                    }
                }
        #pragma unroll
        for (int nj = 0; nj < 4; ++nj) {
            const int cl = wn * 64 + nj * 16 + rl;
            atomicAdd(&sSum[cl], csum[nj]);
            atomicAdd(&sSq[cl], csq[nj]);
        }
        __syncthreads();
        const int slot = (blockIdx.x + blockIdx.y * gridDim.x) & (NPART - 1);
        if (tid < 128 && (n0 + tid) < 300) {
            atomicAdd(&part[slot * 600 + n0 + tid], sSum[tid]);
            atomicAdd(&part[slot * 600 + 300 + n0 + tid], sSq[tid]);
        }
    }
}

// ---------- edge pass: y = ReLU(G[li] + delta.Wc); stats + encoded atomicMax ----------
__launch_bounds__(256)
__global__ void edge_pass(const bf16_t* __restrict__ Gb,
                          const float* __restrict__ last_coors,
                          const float* __restrict__ cur_coors,
                          const int* __restrict__ last_idx,
                          const int* __restrict__ cur_idx,
                          const float* __restrict__ Wc,   // rows 300..302 of W1, 3x300
                          const float* __restrict__ g1,
                          unsigned* __restrict__ zbuf,    // N_cur x 300, encoded, init 0
                          float* __restrict__ part1,
                          int E)
{
    __shared__ float sWc0[300], sWc1[300], sWc2[300];
    __shared__ int sRow[64], sCi[64];
    __shared__ float sD0[64], sD1[64], sD2[64];

    const int tid = threadIdx.x;
    for (int i = tid; i < 300; i += 256) {
        sWc0[i] = Wc[i]; sWc1[i] = Wc[300 + i]; sWc2[i] = Wc[600 + i];
    }

    const int f0 = tid;
    const int f1 = 256 + tid;
    const bool has1 = (f1 < 300);
    const float sgn0 = (g1[f0] < 0.f) ? -1.f : 1.f;
    const float sgn1 = has1 ? ((g1[f1] < 0.f) ? -1.f : 1.f) : 1.f;

    const int e0 = blockIdx.x * 64;
    const int ecnt = min(64, E - e0);

    if (tid < 64 && tid < ecnt) {
        const int e = e0 + tid;
        const int li = last_idx[e], ci = cur_idx[e];
        sRow[tid] = li * 300;
        sCi[tid]  = ci * 300;
        sD0[tid] = last_coors[li * 3 + 0] - cur_coors[ci * 3 + 0];
        sD1[tid] = last_coors[li * 3 + 1] - cur_coors[ci * 3 + 1];
        sD2[tid] = last_coors[li * 3 + 2] - cur_coors[ci * 3 + 2];
    }
    __syncthreads();

    float sum0 = 0.f, sq0 = 0.f, sum1 = 0.f, sq1 = 0.f;
    for (int i = 0; i < ecnt; ++i) {
        const int row = sRow[i], cz = sCi[i];
        const float d0 = sD0[i], d1 = sD1[i], d2 = sD2[i];
        {
            float y = (float)Gb[row + f0]
                    + d0 * sWc0[f0] + d1 * sWc1[f0] + d2 * sWc2[f0];
            y = fmaxf(y, 0.f);
            sum0 += y; sq0 += y * y;
            const unsigned ev = enc_f32(sgn0 * y);
            unsigned* ap = &zbuf[cz + f0];
            if (ev > *ap) atomicMax(ap, ev);   // stale read only under-reads: safe
        }
        if (has1) {
            float y = (float)Gb[row + f1]
                    + d0 * sWc0[f1] + d1 * sWc1[f1] + d2 * sWc2[f1];
            y = fmaxf(y, 0.f);
            sum1 += y; sq1 += y * y;
            const unsigned ev = enc_f32(sgn1 * y);
            unsigned* ap = &zbuf[cz + f1];
            if (ev > *ap) atomicMax(ap, ev);
        }
    }

    const int slot = blockIdx.x & (NPART - 1);
    atomicAdd(&part1[slot * 600 + f0], sum0);
    atomicAdd(&part1[slot * 600 + 300 + f0], sq0);
    if (has1) {
        atomicAdd(&part1[slot * 600 + f1], sum1);
        atomicAdd(&part1[slot * 600 + 300 + f1], sq1);
    }
}

// ---------- reduce partials -> per-feature affine (a, c) ----------
__global__ void stats_finalize(const float* __restrict__ part,
                               const float* __restrict__ g,
                               const float* __restrict__ be,
                               float invCnt, float* __restrict__ ac)
{
    const int t = threadIdx.x;
    if (t >= 300) return;
    float sum = 0.f, sq = 0.f;
    for (int p = 0; p < NPART; ++p) {
        sum += part[p * 600 + t];
        sq  += part[p * 600 + 300 + t];
    }
    const float mean = sum * invCnt;
    const float var = fmaxf(sq * invCnt - mean * mean, 0.f);
    const float inv = rsqrtf(var + 1e-5f);
    const float a = g[t] * inv;
    ac[t] = a;
    ac[300 + t] = be[t] - mean * a;
}

// ---------- decode zbuf -> agg (fp32, in place) ----------
__global__ void agg_finalize(unsigned* __restrict__ zbuf,
                             const float* __restrict__ ac1)
{
    const int t = threadIdx.x;
    if (t >= 300) return;
    const long i = (long)blockIdx.x * 300 + t;
    const unsigned u = zbuf[i];
    float v = 0.f;                      // encoded 0 == no edge wrote == empty segment
    if (u != 0u) v = fabsf(ac1[t]) * dec_f32(u) + ac1[300 + t];
    reinterpret_cast<float*>(zbuf)[i] = v;
}

// ---------- apply BN2 affine to d_out in place ----------
__global__ void finalize_out(float* __restrict__ out,
                             const float* __restrict__ ac2)
{
    const int t = threadIdx.x;
    if (t >= 300) return;
    const long i = (long)blockIdx.x * 300 + t;
    out[i] = ac2[t] * out[i] + ac2[300 + t];
}

extern "C" void kernel_launch(void* const* d_in, const int* in_sizes, int n_in,
                              void* d_out, int out_size, void* d_ws, size_t ws_size,
                              hipStream_t stream)
{
    const float* last_coors    = (const float*)d_in[0];
    const float* last_features = (const float*)d_in[1];
    const float* cur_coors     = (const float*)d_in[2];
    const int*   cur_idx       = (const int*)d_in[3];
    const int*   last_idx      = (const int*)d_in[4];
    const float* W1  = (const float*)d_in[5];
    const float* b1  = (const float*)d_in[6];
    const float* g1  = (const float*)d_in[7];
    const float* be1 = (const float*)d_in[8];
    const float* W2  = (const float*)d_in[9];
    const float* b2  = (const float*)d_in[10];
    const float* g2  = (const float*)d_in[11];
    const float* be2 = (const float*)d_in[12];
    float* out = (float*)d_out;

    const int N_last = in_sizes[0] / 3;
    const int N_cur  = in_sizes[2] / 3;
    const int E      = in_sizes[3];

    char* ws = (char*)d_ws;
    size_t off = 0;
    bf16_t* Gb = (bf16_t*)(ws + off);
    off += (size_t)N_last * 300 * 2;  off = (off + 255) & ~(size_t)255;
    unsigned* zbuf = (unsigned*)(ws + off);
    off += (size_t)N_cur * 300 * 4;   off = (off + 255) & ~(size_t)255;
    bf16_t* WT1 = (bf16_t*)(ws + off); off += (size_t)384 * 320 * 2;
    bf16_t* WT2 = (bf16_t*)(ws + off); off += (size_t)384 * 320 * 2;
    float* part1 = (float*)(ws + off); off += (size_t)NPART * 600 * 4;
    float* part2 = (float*)(ws + off); off += (size_t)NPART * 600 * 4;
    float* ac1   = (float*)(ws + off); off += 600 * 4;
    float* ac2   = (float*)(ws + off); off += 600 * 4;

    hipMemsetAsync(zbuf, 0, (size_t)N_cur * 300 * 4, stream);
    hipMemsetAsync(part1, 0, (size_t)NPART * 600 * 4, stream);
    hipMemsetAsync(part2, 0, (size_t)NPART * 600 * 4, stream);

    // pack W1[:300] and W2 into bf16 [n][k] with zero padding to 384x320
    pack_wt<<<480, 256, 0, stream>>>(W1, WT1);
    pack_wt<<<480, 256, 0, stream>>>(W2, WT2);

    // G = last_features @ W1[:300] + b1  (bf16, MFMA)
    dim3 gridG((N_last + 127) / 128, 3);
    gemm_mfma<0><<<gridG, 256, 0, stream>>>(last_features, 300, N_last,
                                            WT1, b1, Gb, nullptr, nullptr);

    // edge pass: stats1 partials + encoded segment max
    const int nEB = (E + 63) / 64;
    edge_pass<<<nEB, 256, 0, stream>>>(Gb, last_coors, cur_coors,
                                       last_idx, cur_idx,
                                       W1 + 300 * 300, g1, zbuf, part1, E);

    stats_finalize<<<1, 320, 0, stream>>>(part1, g1, be1, 1.0f / (float)E, ac1);
    agg_finalize<<<N_cur, 320, 0, stream>>>(zbuf, ac1);

    // out_pre = ReLU(agg @ W2 + b2), stats2 partials (MFMA)
    dim3 grid2((N_cur + 127) / 128, 3);
    gemm_mfma<1><<<grid2, 256, 0, stream>>>((const float*)zbuf, 300, N_cur,
                                            WT2, b2, nullptr, out, part2);

    stats_finalize<<<1, 320, 0, stream>>>(part2, g2, be2, 1.0f / (float)N_cur, ac2);
    finalize_out<<<N_cur, 320, 0, stream>>>(out, ac2);
}

// Round 3
// 816.946 us; speedup vs baseline: 1.4628x; 1.1905x over previous
//
#include <hip/hip_runtime.h>
#include <hip/hip_bf16.h>

// HGNN: out = BN(ReLU( segmax( BN(ReLU(concat(lf[li], dcoor) @ W1 + b1)) ) @ W2 + b2))
// Decomposition:
//   G[n,f]  = (last_features @ W1[:300] + b1)  as bf16   (MFMA GEMM, no gather)
//   y[e,f]  = ReLU(G[li[e],f] + delta[e] . Wc[:,f])      (edge pass, 3 FMA/elem)
//   Edges counting-sorted by cur_idx -> segment-local running max in registers,
//   one atomicMax flush per segment boundary (not per edge).
//   BN1 is per-feature affine a*y+c, sign(a)=sign(g1) known upfront -> aggregate
//   z = sign(g1)*y, order-preserving uint encoding; encoded-0 => empty segment => 0.
//   out_pre = ReLU(agg @ W2 + b2) -> d_out (MFMA GEMM, stats fused), affine in place.

#define NPART 64
#define SB 256      // scan block
#define CH 128      // edges per edge_pass block

typedef __bf16 bf16_t;
typedef __bf16 bf16x4 __attribute__((ext_vector_type(4)));
typedef __bf16 bf16x8 __attribute__((ext_vector_type(8)));
typedef float f32x4 __attribute__((ext_vector_type(4)));

__device__ __forceinline__ unsigned enc_f32(float x) {
    unsigned u = __float_as_uint(x);
    return (u & 0x80000000u) ? ~u : (u | 0x80000000u);
}
__device__ __forceinline__ float dec_f32(unsigned e) {
    unsigned u = (e & 0x80000000u) ? (e & 0x7fffffffu) : ~e;
    return __uint_as_float(u);
}

// ---------- counting sort: hist -> scan -> scatter ----------
__global__ void hist_k(const int* __restrict__ ci, int E, int* __restrict__ hist)
{
    const int e = blockIdx.x * 256 + threadIdx.x;
    if (e < E) atomicAdd(&hist[ci[e]], 1);
}

__global__ void scan_reduce(const int* __restrict__ hist, int nseg, int* __restrict__ bsum)
{
    __shared__ int s[SB];
    const int tid = threadIdx.x;
    const int i = blockIdx.x * SB + tid;
    s[tid] = (i < nseg) ? hist[i] : 0;
    __syncthreads();
    for (int o = SB / 2; o > 0; o >>= 1) {
        if (tid < o) s[tid] += s[tid + o];
        __syncthreads();
    }
    if (tid == 0) bsum[blockIdx.x] = s[0];
}

// exclusive scan of bsum (nb <= 256), in place
__global__ void scan_top(int* __restrict__ bsum, int nb)
{
    __shared__ int s[SB];
    const int tid = threadIdx.x;
    const int v = (tid < nb) ? bsum[tid] : 0;
    s[tid] = v;
    __syncthreads();
    for (int o = 1; o < SB; o <<= 1) {
        int x = 0;
        if (tid >= o) x = s[tid - o];
        __syncthreads();
        s[tid] += x;
        __syncthreads();
    }
    if (tid < nb) bsum[tid] = s[tid] - v;   // exclusive
}

// per-block exclusive scan + block base -> cnt (running scatter cursor)
__global__ void scan_final(const int* __restrict__ hist, int nseg,
                           const int* __restrict__ bsum, int* __restrict__ cnt)
{
    __shared__ int s[SB];
    const int tid = threadIdx.x;
    const int i = blockIdx.x * SB + tid;
    const int v = (i < nseg) ? hist[i] : 0;
    s[tid] = v;
    __syncthreads();
    for (int o = 1; o < SB; o <<= 1) {
        int x = 0;
        if (tid >= o) x = s[tid - o];
        __syncthreads();
        s[tid] += x;
        __syncthreads();
    }
    if (i < nseg) cnt[i] = s[tid] - v + bsum[blockIdx.x];
}

__global__ void scatter_k(const int* __restrict__ ci, const int* __restrict__ li,
                          int E, int* __restrict__ cnt, int2* __restrict__ sorted)
{
    const int e = blockIdx.x * 256 + threadIdx.x;
    if (e >= E) return;
    const int c = ci[e];
    const int pos = atomicAdd(&cnt[c], 1);
    sorted[pos] = make_int2(li[e], c);
}

// ---------- pack W (fp32 [K=300][N=300] row-major) -> WT bf16 [384][320] = [n][k], zero-padded ----------
__global__ void pack_wt(const float* __restrict__ W, bf16_t* __restrict__ WT)
{
    const int idx = blockIdx.x * 256 + threadIdx.x;   // 384*320 = 122880
    if (idx >= 384 * 320) return;
    const int n = idx / 320, k = idx % 320;
    float v = (n < 300 && k < 300) ? W[k * 300 + n] : 0.f;
    WT[idx] = (bf16_t)v;
}

// ---------- MFMA bf16 GEMM: C[M,300] = A[M,300] @ W + bias ----------
template<int MODE>
__launch_bounds__(256)
__global__ void gemm_mfma(const float* __restrict__ A, int lda, int M,
                          const bf16_t* __restrict__ WT,
                          const float* __restrict__ bias,
                          bf16_t* __restrict__ outBF,
                          float* __restrict__ outF,
                          float* __restrict__ part)
{
    __shared__ bf16_t As[128][72];
    __shared__ bf16_t Bs[128][72];
    __shared__ float sSum[128], sSq[128];

    const int tid  = threadIdx.x;
    const int lane = tid & 63, wv = tid >> 6;
    const int wm = wv & 1, wn = wv >> 1;
    const int m0 = blockIdx.x * 128, n0 = blockIdx.y * 128;
    const int rl = lane & 15, quad = lane >> 4;

    if (MODE == 1 && tid < 128) { sSum[tid] = 0.f; sSq[tid] = 0.f; }

    f32x4 acc[4][4];
    #pragma unroll
    for (int i = 0; i < 4; ++i)
        #pragma unroll
        for (int j = 0; j < 4; ++j)
            acc[i][j] = (f32x4){0.f, 0.f, 0.f, 0.f};

    for (int k0 = 0; k0 < 320; k0 += 64) {
        #pragma unroll
        for (int i = 0; i < 8; ++i) {
            const int id = i * 256 + tid;
            const int r = id >> 4, kc = (id & 15) * 4;
            const int gr = m0 + r, gk = k0 + kc;
            float4 a4 = {0.f, 0.f, 0.f, 0.f};
            if (gr < M && gk < 300)
                a4 = *reinterpret_cast<const float4*>(&A[(long)gr * lda + gk]);
            bf16x4 b4 = {(bf16_t)a4.x, (bf16_t)a4.y, (bf16_t)a4.z, (bf16_t)a4.w};
            *reinterpret_cast<bf16x4*>(&As[r][kc]) = b4;
        }
        #pragma unroll
        for (int i = 0; i < 4; ++i) {
            const int id = i * 256 + tid;
            const int n = id >> 3, kc = (id & 7) * 8;
            bf16x8 w8 = *reinterpret_cast<const bf16x8*>(&WT[(long)(n0 + n) * 320 + k0 + kc]);
            *reinterpret_cast<bf16x8*>(&Bs[n][kc]) = w8;
        }
        __syncthreads();

        #pragma unroll
        for (int kk = 0; kk < 2; ++kk) {
            const int kb = kk * 32 + quad * 8;
            bf16x8 af[4], bfr[4];
            #pragma unroll
            for (int mi = 0; mi < 4; ++mi)
                af[mi] = *reinterpret_cast<const bf16x8*>(&As[wm * 64 + mi * 16 + rl][kb]);
            #pragma unroll
            for (int nj = 0; nj < 4; ++nj)
                bfr[nj] = *reinterpret_cast<const bf16x8*>(&Bs[wn * 64 + nj * 16 + rl][kb]);
            #pragma unroll
            for (int mi = 0; mi < 4; ++mi)
                #pragma unroll
                for (int nj = 0; nj < 4; ++nj)
                    acc[mi][nj] = __builtin_amdgcn_mfma_f32_16x16x32_bf16(
                        af[mi], bfr[nj], acc[mi][nj], 0, 0, 0);
        }
        __syncthreads();
    }

    if (MODE == 0) {
        #pragma unroll
        for (int mi = 0; mi < 4; ++mi)
            #pragma unroll
            for (int nj = 0; nj < 4; ++nj)
                #pragma unroll
                for (int reg = 0; reg < 4; ++reg) {
                    const int r = m0 + wm * 64 + mi * 16 + quad * 4 + reg;
                    const int c = n0 + wn * 64 + nj * 16 + rl;
                    if (r < M && c < 300)
                        outBF[(long)r * 300 + c] = (bf16_t)(acc[mi][nj][reg] + bias[c]);
                }
    } else {
        float csum[4] = {}, csq[4] = {};
        #pragma unroll
        for (int mi = 0; mi < 4; ++mi)
            #pragma unroll
            for (int nj = 0; nj < 4; ++nj)
                #pragma unroll
                for (int reg = 0; reg < 4; ++reg) {
                    const int r = m0 + wm * 64 + mi * 16 + quad * 4 + reg;
                    const int c = n0 + wn * 64 + nj * 16 + rl;
                    if (r < M && c < 300) {
                        float v = fmaxf(acc[mi][nj][reg] + bias[c], 0.f);
                        outF[(long)r * 300 + c] = v;
                        csum[nj] += v; csq[nj] += v * v;
                    }
                }
        #pragma unroll
        for (int nj = 0; nj < 4; ++nj) {
            const int cl = wn * 64 + nj * 16 + rl;
            atomicAdd(&sSum[cl], csum[nj]);
            atomicAdd(&sSq[cl], csq[nj]);
        }
        __syncthreads();
        const int slot = (blockIdx.x + blockIdx.y * gridDim.x) & (NPART - 1);
        if (tid < 128 && (n0 + tid) < 300) {
            atomicAdd(&part[slot * 600 + n0 + tid], sSum[tid]);
            atomicAdd(&part[slot * 600 + 300 + n0 + tid], sSq[tid]);
        }
    }
}

// ---------- edge pass over SORTED edges: register running-max per segment ----------
__launch_bounds__(320)
__global__ void edge_pass(const bf16_t* __restrict__ Gb,
                          const float* __restrict__ last_coors,
                          const float* __restrict__ cur_coors,
                          const int2* __restrict__ sorted,   // (li, ci), sorted by ci
                          const float* __restrict__ Wc,      // rows 300..302 of W1, 3x300
                          const float* __restrict__ g1,
                          unsigned* __restrict__ zbuf,       // N_cur x 300, encoded, init 0
                          float* __restrict__ part1,
                          int E)
{
    __shared__ float sWc0[300], sWc1[300], sWc2[300];
    __shared__ int sRow[CH], sCi[CH];
    __shared__ float sD0[CH], sD1[CH], sD2[CH];

    const int tid = threadIdx.x;
    for (int i = tid; i < 300; i += 320) {
        sWc0[i] = Wc[i]; sWc1[i] = Wc[300 + i]; sWc2[i] = Wc[600 + i];
    }

    const int e0 = blockIdx.x * CH;
    const int ecnt = min(CH, E - e0);

    for (int i = tid; i < ecnt; i += 320) {
        const int2 r = sorted[e0 + i];
        const int li = r.x, ci = r.y;
        sRow[i] = li * 300;
        sCi[i]  = ci;
        sD0[i] = last_coors[li * 3 + 0] - cur_coors[ci * 3 + 0];
        sD1[i] = last_coors[li * 3 + 1] - cur_coors[ci * 3 + 1];
        sD2[i] = last_coors[li * 3 + 2] - cur_coors[ci * 3 + 2];
    }
    __syncthreads();

    const int t = tid;
    const bool active = (t < 300);
    const float sgn = (active && g1[t] < 0.f) ? -1.f : 1.f;
    const float w0 = active ? sWc0[t] : 0.f;
    const float w1 = active ? sWc1[t] : 0.f;
    const float w2 = active ? sWc2[t] : 0.f;

    int cur = sCi[0];
    float m = -3.4e38f, sum = 0.f, sq = 0.f;

    for (int i = 0; i < ecnt; ++i) {
        const int ci = sCi[i];
        if (ci != cur) {                       // block-uniform branch
            if (active) atomicMax(&zbuf[(long)cur * 300 + t], enc_f32(m));
            cur = ci;
            m = -3.4e38f;
        }
        if (active) {
            float y = (float)Gb[sRow[i] + t]
                    + sD0[i] * w0 + sD1[i] * w1 + sD2[i] * w2;
            y = fmaxf(y, 0.f);
            sum += y; sq += y * y;
            m = fmaxf(m, sgn * y);
        }
    }
    if (active && ecnt > 0)
        atomicMax(&zbuf[(long)cur * 300 + t], enc_f32(m));

    const int slot = blockIdx.x & (NPART - 1);
    if (active) {
        atomicAdd(&part1[slot * 600 + t], sum);
        atomicAdd(&part1[slot * 600 + 300 + t], sq);
    }
}

// ---------- reduce partials -> per-feature affine (a, c) ----------
__global__ void stats_finalize(const float* __restrict__ part,
                               const float* __restrict__ g,
                               const float* __restrict__ be,
                               float invCnt, float* __restrict__ ac)
{
    const int t = threadIdx.x;
    if (t >= 300) return;
    float sum = 0.f, sq = 0.f;
    for (int p = 0; p < NPART; ++p) {
        sum += part[p * 600 + t];
        sq  += part[p * 600 + 300 + t];
    }
    const float mean = sum * invCnt;
    const float var = fmaxf(sq * invCnt - mean * mean, 0.f);
    const float inv = rsqrtf(var + 1e-5f);
    const float a = g[t] * inv;
    ac[t] = a;
    ac[300 + t] = be[t] - mean * a;
}

// ---------- decode zbuf -> agg (fp32, in place) ----------
__global__ void agg_finalize(unsigned* __restrict__ zbuf,
                             const float* __restrict__ ac1)
{
    const int t = threadIdx.x;
    if (t >= 300) return;
    const long i = (long)blockIdx.x * 300 + t;
    const unsigned u = zbuf[i];
    float v = 0.f;                      // encoded 0 == no edge wrote == empty segment
    if (u != 0u) v = fabsf(ac1[t]) * dec_f32(u) + ac1[300 + t];
    reinterpret_cast<float*>(zbuf)[i] = v;
}

// ---------- apply BN2 affine to d_out in place ----------
__global__ void finalize_out(float* __restrict__ out,
                             const float* __restrict__ ac2)
{
    const int t = threadIdx.x;
    if (t >= 300) return;
    const long i = (long)blockIdx.x * 300 + t;
    out[i] = ac2[t] * out[i] + ac2[300 + t];
}

extern "C" void kernel_launch(void* const* d_in, const int* in_sizes, int n_in,
                              void* d_out, int out_size, void* d_ws, size_t ws_size,
                              hipStream_t stream)
{
    const float* last_coors    = (const float*)d_in[0];
    const float* last_features = (const float*)d_in[1];
    const float* cur_coors     = (const float*)d_in[2];
    const int*   cur_idx       = (const int*)d_in[3];
    const int*   last_idx      = (const int*)d_in[4];
    const float* W1  = (const float*)d_in[5];
    const float* b1  = (const float*)d_in[6];
    const float* g1  = (const float*)d_in[7];
    const float* be1 = (const float*)d_in[8];
    const float* W2  = (const float*)d_in[9];
    const float* b2  = (const float*)d_in[10];
    const float* g2  = (const float*)d_in[11];
    const float* be2 = (const float*)d_in[12];
    float* out = (float*)d_out;

    const int N_last = in_sizes[0] / 3;
    const int N_cur  = in_sizes[2] / 3;
    const int E      = in_sizes[3];

    const int nb1 = (N_cur + SB - 1) / SB;      // scan blocks (<=256 for N_cur<=65536)

    char* ws = (char*)d_ws;
    size_t off = 0;
    bf16_t* Gb = (bf16_t*)(ws + off);
    off += (size_t)N_last * 300 * 2;  off = (off + 255) & ~(size_t)255;
    unsigned* zbuf = (unsigned*)(ws + off);
    off += (size_t)N_cur * 300 * 4;   off = (off + 255) & ~(size_t)255;
    int2* sorted = (int2*)(ws + off);  off += (size_t)E * 8;
    int* hist = (int*)(ws + off);      off += (size_t)nb1 * SB * 4;
    int* cnt  = (int*)(ws + off);      off += (size_t)nb1 * SB * 4;
    int* bsum = (int*)(ws + off);      off += 256 * 4;
    bf16_t* WT1 = (bf16_t*)(ws + off); off += (size_t)384 * 320 * 2;
    bf16_t* WT2 = (bf16_t*)(ws + off); off += (size_t)384 * 320 * 2;
    float* part1 = (float*)(ws + off); off += (size_t)NPART * 600 * 4;
    float* part2 = (float*)(ws + off); off += (size_t)NPART * 600 * 4;
    float* ac1   = (float*)(ws + off); off += 600 * 4;
    float* ac2   = (float*)(ws + off); off += 600 * 4;

    hipMemsetAsync(zbuf, 0, (size_t)N_cur * 300 * 4, stream);
    hipMemsetAsync(hist, 0, (size_t)nb1 * SB * 4, stream);
    hipMemsetAsync(part1, 0, (size_t)NPART * 600 * 4, stream);
    hipMemsetAsync(part2, 0, (size_t)NPART * 600 * 4, stream);

    // ---- counting sort of edges by cur_idx ----
    hist_k<<<(E + 255) / 256, 256, 0, stream>>>(cur_idx, E, hist);
    scan_reduce<<<nb1, SB, 0, stream>>>(hist, N_cur, bsum);
    scan_top<<<1, SB, 0, stream>>>(bsum, nb1);
    scan_final<<<nb1, SB, 0, stream>>>(hist, N_cur, bsum, cnt);
    scatter_k<<<(E + 255) / 256, 256, 0, stream>>>(cur_idx, last_idx, E, cnt, sorted);

    // pack W1[:300] and W2 into bf16 [n][k] with zero padding to 384x320
    pack_wt<<<480, 256, 0, stream>>>(W1, WT1);
    pack_wt<<<480, 256, 0, stream>>>(W2, WT2);

    // G = last_features @ W1[:300] + b1  (bf16, MFMA)
    dim3 gridG((N_last + 127) / 128, 3);
    gemm_mfma<0><<<gridG, 256, 0, stream>>>(last_features, 300, N_last,
                                            WT1, b1, Gb, nullptr, nullptr);

    // edge pass over sorted edges
    const int nEB = (E + CH - 1) / CH;
    edge_pass<<<nEB, 320, 0, stream>>>(Gb, last_coors, cur_coors, sorted,
                                       W1 + 300 * 300, g1, zbuf, part1, E);

    stats_finalize<<<1, 320, 0, stream>>>(part1, g1, be1, 1.0f / (float)E, ac1);
    agg_finalize<<<N_cur, 320, 0, stream>>>(zbuf, ac1);

    // out_pre = ReLU(agg @ W2 + b2), stats2 partials (MFMA)
    dim3 grid2((N_cur + 127) / 128, 3);
    gemm_mfma<1><<<grid2, 256, 0, stream>>>((const float*)zbuf, 300, N_cur,
                                            WT2, b2, nullptr, out, part2);

    stats_finalize<<<1, 320, 0, stream>>>(part2, g2, be2, 1.0f / (float)N_cur, ac2);
    finalize_out<<<N_cur, 320, 0, stream>>>(out, ac2);
}

// Round 4
// 708.034 us; speedup vs baseline: 1.6878x; 1.1538x over previous
//
#include <hip/hip_runtime.h>
#include <hip/hip_bf16.h>

// HGNN: out = BN(ReLU( segmax( BN(ReLU(concat(lf[li], dcoor) @ W1 + b1)) ) @ W2 + b2))
//   G[n,f]  = (last_features @ W1[:300] + b1)  as bf16   (MFMA GEMM, no gather)
//   y[e,f]  = ReLU(G[li[e],f] + delta[e] . Wc[:,f])      (edge pass, 3 FMA/elem)
//   Edges counting-sorted by cur_idx -> segment-local running max in registers,
//   one atomicMax flush per segment boundary; 8-deep load batching for MLP.
//   BN1 affine a*y+c with sign(a)=sign(g1) known upfront; aggregate z=sgn*y via
//   order-preserving uint encoding; encoded-0 => empty segment => 0.
//   out_pre = ReLU(agg @ W2 + b2) -> d_out (MFMA GEMM, stats fused), affine in place.
// Workspace aliasing: region1 = Alf (bf16 A for gemm0) then zbuf;
//                     region0 = Gb then Ab2 (bf16 A for gemm1).

#define NPART 64
#define SB 256      // scan block
#define CH 256      // edges per edge_pass block
#define UNR 8       // edge_pass load batch depth

typedef __bf16 bf16_t;
typedef __bf16 bf16x4 __attribute__((ext_vector_type(4)));
typedef __bf16 bf16x8 __attribute__((ext_vector_type(8)));
typedef float f32x4 __attribute__((ext_vector_type(4)));

__device__ __forceinline__ unsigned enc_f32(float x) {
    unsigned u = __float_as_uint(x);
    return (u & 0x80000000u) ? ~u : (u | 0x80000000u);
}
__device__ __forceinline__ float dec_f32(unsigned e) {
    unsigned u = (e & 0x80000000u) ? (e & 0x7fffffffu) : ~e;
    return __uint_as_float(u);
}

// ---------- counting sort: hist -> scan -> scatter ----------
__global__ void hist_k(const int* __restrict__ ci, int E, int* __restrict__ hist)
{
    const int e = blockIdx.x * 256 + threadIdx.x;
    if (e < E) atomicAdd(&hist[ci[e]], 1);
}

__global__ void scan_reduce(const int* __restrict__ hist, int nseg, int* __restrict__ bsum)
{
    __shared__ int s[SB];
    const int tid = threadIdx.x;
    const int i = blockIdx.x * SB + tid;
    s[tid] = (i < nseg) ? hist[i] : 0;
    __syncthreads();
    for (int o = SB / 2; o > 0; o >>= 1) {
        if (tid < o) s[tid] += s[tid + o];
        __syncthreads();
    }
    if (tid == 0) bsum[blockIdx.x] = s[0];
}

__global__ void scan_top(int* __restrict__ bsum, int nb)
{
    __shared__ int s[SB];
    const int tid = threadIdx.x;
    const int v = (tid < nb) ? bsum[tid] : 0;
    s[tid] = v;
    __syncthreads();
    for (int o = 1; o < SB; o <<= 1) {
        int x = 0;
        if (tid >= o) x = s[tid - o];
        __syncthreads();
        s[tid] += x;
        __syncthreads();
    }
    if (tid < nb) bsum[tid] = s[tid] - v;   // exclusive
}

__global__ void scan_final(const int* __restrict__ hist, int nseg,
                           const int* __restrict__ bsum, int* __restrict__ cnt)
{
    __shared__ int s[SB];
    const int tid = threadIdx.x;
    const int i = blockIdx.x * SB + tid;
    const int v = (i < nseg) ? hist[i] : 0;
    s[tid] = v;
    __syncthreads();
    for (int o = 1; o < SB; o <<= 1) {
        int x = 0;
        if (tid >= o) x = s[tid - o];
        __syncthreads();
        s[tid] += x;
        __syncthreads();
    }
    if (i < nseg) cnt[i] = s[tid] - v + bsum[blockIdx.x];
}

__global__ void scatter_k(const int* __restrict__ ci, const int* __restrict__ li,
                          int E, int* __restrict__ cnt, int2* __restrict__ sorted)
{
    const int e = blockIdx.x * 256 + threadIdx.x;
    if (e >= E) return;
    const int c = ci[e];
    const int pos = atomicAdd(&cnt[c], 1);
    sorted[pos] = make_int2(li[e], c);
}

// ---------- pack W (fp32 [300][300] row-major) -> WT bf16 [384][320] = [n][k], zero-padded ----------
__global__ void pack_wt(const float* __restrict__ W, bf16_t* __restrict__ WT)
{
    const int idx = blockIdx.x * 256 + threadIdx.x;
    if (idx >= 384 * 320) return;
    const int n = idx / 320, k = idx % 320;
    float v = (n < 300 && k < 300) ? W[k * 300 + n] : 0.f;
    WT[idx] = (bf16_t)v;
}

// ---------- convert lf fp32 [M][300] -> bf16 [M][320] zero-padded ----------
__global__ void cvt_lf(const float* __restrict__ lf, bf16_t* __restrict__ out, int M)
{
    const int idx = blockIdx.x * 256 + threadIdx.x;   // one bf16x8 chunk each
    const int r = idx / 40, c8 = (idx % 40) * 8;
    if (r >= M) return;
    bf16x8 v = {};
    if (c8 + 8 <= 300) {
        const float4 a = *reinterpret_cast<const float4*>(&lf[(long)r * 300 + c8]);
        const float4 b = *reinterpret_cast<const float4*>(&lf[(long)r * 300 + c8 + 4]);
        v = (bf16x8){(bf16_t)a.x, (bf16_t)a.y, (bf16_t)a.z, (bf16_t)a.w,
                     (bf16_t)b.x, (bf16_t)b.y, (bf16_t)b.z, (bf16_t)b.w};
    } else if (c8 < 300) {   // c8 == 296
        const float4 a = *reinterpret_cast<const float4*>(&lf[(long)r * 300 + c8]);
        v[0] = (bf16_t)a.x; v[1] = (bf16_t)a.y; v[2] = (bf16_t)a.z; v[3] = (bf16_t)a.w;
    }
    *reinterpret_cast<bf16x8*>(&out[(long)r * 320 + c8]) = v;
}

// ---------- MFMA bf16 GEMM: C[M,300] = A[M,:300] @ W + bias ----------
// A bf16 [M][320] zero-padded; WT bf16 [384][320] = [n][k].
// Tiles: 128 (M) x 160 (N), BK=64; 4 waves in 2x2 (wave: 64 x 80).
// MODE 0: store bf16 to outBF. MODE 1: ReLU, fp32 to outF, stats partials.
template<int MODE>
__launch_bounds__(256)
__global__ void gemm_mfma(const bf16_t* __restrict__ A, int M,
                          const bf16_t* __restrict__ WT,
                          const float* __restrict__ bias,
                          bf16_t* __restrict__ outBF,
                          float* __restrict__ outF,
                          float* __restrict__ part)
{
    __shared__ bf16_t As[128][72];
    __shared__ bf16_t Bs[160][72];
    __shared__ float sSum[160], sSq[160];

    const int tid  = threadIdx.x;
    const int lane = tid & 63, wv = tid >> 6;
    const int wm = wv & 1, wn = wv >> 1;
    const int m0 = blockIdx.x * 128, n0 = blockIdx.y * 160;
    const int rl = lane & 15, quad = lane >> 4;

    if (MODE == 1 && tid < 160) { sSum[tid] = 0.f; sSq[tid] = 0.f; }

    f32x4 acc[4][5];
    #pragma unroll
    for (int i = 0; i < 4; ++i)
        #pragma unroll
        for (int j = 0; j < 5; ++j)
            acc[i][j] = (f32x4){0.f, 0.f, 0.f, 0.f};

    for (int k0 = 0; k0 < 320; k0 += 64) {
        // A tile: 128 rows x 64 k (bf16x8, clamped rows, no masks)
        #pragma unroll
        for (int i = 0; i < 4; ++i) {
            const int id = i * 256 + tid;
            const int r = id >> 3, kc = (id & 7) * 8;
            const int gr = min(m0 + r, M - 1);
            bf16x8 a8 = *reinterpret_cast<const bf16x8*>(&A[(long)gr * 320 + k0 + kc]);
            *reinterpret_cast<bf16x8*>(&As[r][kc]) = a8;
        }
        // B tile: 160 rows x 64 k
        #pragma unroll
        for (int i = 0; i < 5; ++i) {
            const int id = i * 256 + tid;
            const int n = id >> 3, kc = (id & 7) * 8;
            bf16x8 w8 = *reinterpret_cast<const bf16x8*>(&WT[(long)(n0 + n) * 320 + k0 + kc]);
            *reinterpret_cast<bf16x8*>(&Bs[n][kc]) = w8;
        }
        __syncthreads();

        #pragma unroll
        for (int kk = 0; kk < 2; ++kk) {
            const int kb = kk * 32 + quad * 8;
            bf16x8 af[4], bfr[5];
            #pragma unroll
            for (int mi = 0; mi < 4; ++mi)
                af[mi] = *reinterpret_cast<const bf16x8*>(&As[wm * 64 + mi * 16 + rl][kb]);
            #pragma unroll
            for (int nj = 0; nj < 5; ++nj)
                bfr[nj] = *reinterpret_cast<const bf16x8*>(&Bs[wn * 80 + nj * 16 + rl][kb]);
            #pragma unroll
            for (int mi = 0; mi < 4; ++mi)
                #pragma unroll
                for (int nj = 0; nj < 5; ++nj)
                    acc[mi][nj] = __builtin_amdgcn_mfma_f32_16x16x32_bf16(
                        af[mi], bfr[nj], acc[mi][nj], 0, 0, 0);
        }
        __syncthreads();
    }

    // epilogue: C/D layout col = lane&15, row = quad*4 + reg
    if (MODE == 0) {
        #pragma unroll
        for (int mi = 0; mi < 4; ++mi)
            #pragma unroll
            for (int nj = 0; nj < 5; ++nj)
                #pragma unroll
                for (int reg = 0; reg < 4; ++reg) {
                    const int r = m0 + wm * 64 + mi * 16 + quad * 4 + reg;
                    const int c = n0 + wn * 80 + nj * 16 + rl;
                    if (r < M && c < 300)
                        outBF[(long)r * 300 + c] = (bf16_t)(acc[mi][nj][reg] + bias[c]);
                }
    } else {
        float csum[5] = {}, csq[5] = {};
        #pragma unroll
        for (int mi = 0; mi < 4; ++mi)
            #pragma unroll
            for (int nj = 0; nj < 5; ++nj)
                #pragma unroll
                for (int reg = 0; reg < 4; ++reg) {
                    const int r = m0 + wm * 64 + mi * 16 + quad * 4 + reg;
                    const int c = n0 + wn * 80 + nj * 16 + rl;
                    if (r < M && c < 300) {
                        float v = fmaxf(acc[mi][nj][reg] + bias[c], 0.f);
                        outF[(long)r * 300 + c] = v;
                        csum[nj] += v; csq[nj] += v * v;
                    }
                }
        #pragma unroll
        for (int nj = 0; nj < 5; ++nj) {
            const int cl = wn * 80 + nj * 16 + rl;
            atomicAdd(&sSum[cl], csum[nj]);
            atomicAdd(&sSq[cl], csq[nj]);
        }
        __syncthreads();
        const int slot = (blockIdx.x + blockIdx.y * gridDim.x) & (NPART - 1);
        if (tid < 160 && (n0 + tid) < 300) {
            atomicAdd(&part[slot * 600 + n0 + tid], sSum[tid]);
            atomicAdd(&part[slot * 600 + 300 + n0 + tid], sSq[tid]);
        }
    }
}

// ---------- edge pass over SORTED edges: batched loads + register running-max ----------
__launch_bounds__(320)
__global__ void edge_pass(const bf16_t* __restrict__ Gb,
                          const float* __restrict__ last_coors,
                          const float* __restrict__ cur_coors,
                          const int2* __restrict__ sorted,   // (li, ci), sorted by ci
                          const float* __restrict__ Wc,      // rows 300..302 of W1, 3x300
                          const float* __restrict__ g1,
                          unsigned* __restrict__ zbuf,       // N_cur x 300, encoded, init 0
                          float* __restrict__ part1,
                          int E)
{
    __shared__ float sWc0[300], sWc1[300], sWc2[300];
    __shared__ int sRow[CH], sCi[CH];
    __shared__ float sD0[CH], sD1[CH], sD2[CH];

    const int tid = threadIdx.x;
    for (int i = tid; i < 300; i += 320) {
        sWc0[i] = Wc[i]; sWc1[i] = Wc[300 + i]; sWc2[i] = Wc[600 + i];
    }

    const int e0 = blockIdx.x * CH;
    const int ecnt = min(CH, E - e0);

    for (int i = tid; i < ecnt; i += 320) {
        const int2 r = sorted[e0 + i];
        const int li = r.x, ci = r.y;
        sRow[i] = li * 300;
        sCi[i]  = ci;
        sD0[i] = last_coors[li * 3 + 0] - cur_coors[ci * 3 + 0];
        sD1[i] = last_coors[li * 3 + 1] - cur_coors[ci * 3 + 1];
        sD2[i] = last_coors[li * 3 + 2] - cur_coors[ci * 3 + 2];
    }
    __syncthreads();

    const int t = tid;
    const bool active = (t < 300);
    const float sgn = (active && g1[t] < 0.f) ? -1.f : 1.f;
    const float w0 = active ? sWc0[t] : 0.f;
    const float w1 = active ? sWc1[t] : 0.f;
    const float w2 = active ? sWc2[t] : 0.f;

    int cur = (ecnt > 0) ? sCi[0] : 0;
    float m = -3.4e38f, sum = 0.f, sq = 0.f;

    int i = 0;
    for (; i + UNR <= ecnt; i += UNR) {
        float g[UNR];
        #pragma unroll
        for (int j = 0; j < UNR; ++j)
            g[j] = active ? (float)Gb[sRow[i + j] + t] : 0.f;   // 8 loads in flight
        #pragma unroll
        for (int j = 0; j < UNR; ++j) {
            const int ci = sCi[i + j];
            if (ci != cur) {                   // block-uniform branch
                if (active) atomicMax(&zbuf[(long)cur * 300 + t], enc_f32(m));
                cur = ci;
                m = -3.4e38f;
            }
            float y = fmaxf(g[j] + sD0[i + j] * w0 + sD1[i + j] * w1 + sD2[i + j] * w2, 0.f);
            sum += y; sq += y * y;
            m = fmaxf(m, sgn * y);
        }
    }
    for (; i < ecnt; ++i) {
        const int ci = sCi[i];
        if (ci != cur) {
            if (active) atomicMax(&zbuf[(long)cur * 300 + t], enc_f32(m));
            cur = ci;
            m = -3.4e38f;
        }
        float y = active ? (float)Gb[sRow[i] + t] : 0.f;
        y = fmaxf(y + sD0[i] * w0 + sD1[i] * w1 + sD2[i] * w2, 0.f);
        sum += y; sq += y * y;
        m = fmaxf(m, sgn * y);
    }
    if (active && ecnt > 0)
        atomicMax(&zbuf[(long)cur * 300 + t], enc_f32(m));

    const int slot = blockIdx.x & (NPART - 1);
    if (active) {
        atomicAdd(&part1[slot * 600 + t], sum);
        atomicAdd(&part1[slot * 600 + 300 + t], sq);
    }
}

// ---------- reduce partials -> per-feature affine (a, c) ----------
__global__ void stats_finalize(const float* __restrict__ part,
                               const float* __restrict__ g,
                               const float* __restrict__ be,
                               float invCnt, float* __restrict__ ac)
{
    const int t = threadIdx.x;
    if (t >= 300) return;
    float sum = 0.f, sq = 0.f;
    for (int p = 0; p < NPART; ++p) {
        sum += part[p * 600 + t];
        sq  += part[p * 600 + 300 + t];
    }
    const float mean = sum * invCnt;
    const float var = fmaxf(sq * invCnt - mean * mean, 0.f);
    const float inv = rsqrtf(var + 1e-5f);
    const float a = g[t] * inv;
    ac[t] = a;
    ac[300 + t] = be[t] - mean * a;
}

// ---------- decode zbuf -> Ab2 bf16 [N_cur][320] zero-padded ----------
__global__ void agg_finalize(const unsigned* __restrict__ zbuf,
                             const float* __restrict__ ac1,
                             bf16_t* __restrict__ Ab2)
{
    const int t = threadIdx.x;   // 320 threads
    float v = 0.f;
    if (t < 300) {
        const unsigned u = zbuf[(long)blockIdx.x * 300 + t];
        if (u != 0u) v = fabsf(ac1[t]) * dec_f32(u) + ac1[300 + t];
    }
    Ab2[(long)blockIdx.x * 320 + t] = (bf16_t)v;
}

// ---------- apply BN2 affine to d_out in place ----------
__global__ void finalize_out(float* __restrict__ out,
                             const float* __restrict__ ac2)
{
    const int t = threadIdx.x;
    if (t >= 300) return;
    const long i = (long)blockIdx.x * 300 + t;
    out[i] = ac2[t] * out[i] + ac2[300 + t];
}

extern "C" void kernel_launch(void* const* d_in, const int* in_sizes, int n_in,
                              void* d_out, int out_size, void* d_ws, size_t ws_size,
                              hipStream_t stream)
{
    const float* last_coors    = (const float*)d_in[0];
    const float* last_features = (const float*)d_in[1];
    const float* cur_coors     = (const float*)d_in[2];
    const int*   cur_idx       = (const int*)d_in[3];
    const int*   last_idx      = (const int*)d_in[4];
    const float* W1  = (const float*)d_in[5];
    const float* b1  = (const float*)d_in[6];
    const float* g1  = (const float*)d_in[7];
    const float* be1 = (const float*)d_in[8];
    const float* W2  = (const float*)d_in[9];
    const float* b2  = (const float*)d_in[10];
    const float* g2  = (const float*)d_in[11];
    const float* be2 = (const float*)d_in[12];
    float* out = (float*)d_out;

    const int N_last = in_sizes[0] / 3;
    const int N_cur  = in_sizes[2] / 3;
    const int E      = in_sizes[3];

    const int nb1 = (N_cur + SB - 1) / SB;

    // ---- workspace (aliased regions) ----
    char* ws = (char*)d_ws;
    size_t off = 0;
    // region0: Gb (N_last x 300 bf16) -> later Ab2 (N_cur x 320 bf16)
    const size_t sz_r0 = (size_t)N_last * 300 * 2;
    bf16_t* Gb  = (bf16_t*)(ws + off);
    bf16_t* Ab2 = (bf16_t*)(ws + off);
    off += sz_r0; off = (off + 255) & ~(size_t)255;
    // region1: Alf (N_last x 320 bf16) -> later zbuf (N_cur x 300 u32)
    const size_t sz_alf = (size_t)N_last * 320 * 2;
    const size_t sz_zb  = (size_t)N_cur * 300 * 4;
    bf16_t* Alf = (bf16_t*)(ws + off);
    unsigned* zbuf = (unsigned*)(ws + off);
    off += (sz_alf > sz_zb ? sz_alf : sz_zb); off = (off + 255) & ~(size_t)255;
    int2* sorted = (int2*)(ws + off);  off += (size_t)E * 8;
    int* hist = (int*)(ws + off);      off += (size_t)nb1 * SB * 4;
    int* cnt  = (int*)(ws + off);      off += (size_t)nb1 * SB * 4;
    int* bsum = (int*)(ws + off);      off += 256 * 4;
    bf16_t* WT1 = (bf16_t*)(ws + off); off += (size_t)384 * 320 * 2;
    bf16_t* WT2 = (bf16_t*)(ws + off); off += (size_t)384 * 320 * 2;
    float* part1 = (float*)(ws + off); off += (size_t)NPART * 600 * 4;
    float* part2 = (float*)(ws + off); off += (size_t)NPART * 600 * 4;
    float* ac1   = (float*)(ws + off); off += 600 * 4;
    float* ac2   = (float*)(ws + off); off += 600 * 4;

    hipMemsetAsync(hist, 0, (size_t)nb1 * SB * 4, stream);
    hipMemsetAsync(part1, 0, (size_t)NPART * 600 * 4, stream);
    hipMemsetAsync(part2, 0, (size_t)NPART * 600 * 4, stream);

    // ---- counting sort of edges by cur_idx (independent of regions 0/1) ----
    hist_k<<<(E + 255) / 256, 256, 0, stream>>>(cur_idx, E, hist);
    scan_reduce<<<nb1, SB, 0, stream>>>(hist, N_cur, bsum);
    scan_top<<<1, SB, 0, stream>>>(bsum, nb1);
    scan_final<<<nb1, SB, 0, stream>>>(hist, N_cur, bsum, cnt);
    scatter_k<<<(E + 255) / 256, 256, 0, stream>>>(cur_idx, last_idx, E, cnt, sorted);

    // ---- weights + A conversion ----
    pack_wt<<<480, 256, 0, stream>>>(W1, WT1);
    pack_wt<<<480, 256, 0, stream>>>(W2, WT2);
    cvt_lf<<<((N_last * 40) + 255) / 256, 256, 0, stream>>>(last_features, Alf, N_last);

    // G = last_features @ W1[:300] + b1  (bf16 MFMA; reads Alf, writes Gb)
    dim3 gridG((N_last + 127) / 128, 2);
    gemm_mfma<0><<<gridG, 256, 0, stream>>>(Alf, N_last, WT1, b1, Gb, nullptr, nullptr);

    // zbuf overwrites Alf (stream-ordered after gemm0)
    hipMemsetAsync(zbuf, 0, sz_zb, stream);

    // edge pass over sorted edges
    const int nEB = (E + CH - 1) / CH;
    edge_pass<<<nEB, 320, 0, stream>>>(Gb, last_coors, cur_coors, sorted,
                                       W1 + 300 * 300, g1, zbuf, part1, E);

    stats_finalize<<<1, 320, 0, stream>>>(part1, g1, be1, 1.0f / (float)E, ac1);
    // Ab2 overwrites Gb (Gb consumed by edge_pass)
    agg_finalize<<<N_cur, 320, 0, stream>>>(zbuf, ac1, Ab2);

    // out_pre = ReLU(agg @ W2 + b2), stats2 partials (bf16 MFMA)
    dim3 grid2((N_cur + 127) / 128, 2);
    gemm_mfma<1><<<grid2, 256, 0, stream>>>(Ab2, N_cur, WT2, b2, nullptr, out, part2);

    stats_finalize<<<1, 320, 0, stream>>>(part2, g2, be2, 1.0f / (float)N_cur, ac2);
    finalize_out<<<N_cur, 320, 0, stream>>>(out, ac2);
}